// Round 1
// baseline (959.019 us; speedup 1.0000x reference)
//
#include <hip/hip_runtime.h>

// RandomlyLocalizedConformalRiskControl on MI355X.
// ws layout (bytes), total ~120.2 MB:
//   cal_res  f32 [256][65536]            @ 0          (64 MB)
//   test_res f32 [32][65536]             @ 67108864   (8 MB)
//   grouped  u16 [256][65536]            @ 75497472   (32 MB)   low-16 bits of score, counting-sorted by hi-16 bucket
//   cdf      u32 [256][CDF_STRIDE]       @ 109051904  (16 MB)   exclusive CDF over 16256 hi-16 buckets; [HB]=pos
//   gpart    f32 [8][32][256]            @ 125714432
//   cc f32[256], tt f32[32], Q f32[32*256], wlast f32[32], lam f32[32]

#define NPIX 65536
#define HB 16256            // buckets = float_bits >> 16 for scores in (0, 1.0]
#define CDF_STRIDE 16272
#define ALPHA 0.1f

#define OFF_CALRES   0
#define OFF_TESTRES  67108864u
#define OFF_GROUPED  75497472u
#define OFF_CDF      109051904u
#define OFF_GPART    125714432u
#define OFF_CC       125976576u
#define OFF_TT       125977600u
#define OFF_Q        125977728u
#define OFF_WLAST    126010496u
#define OFF_LAM      126010624u

__device__ __forceinline__ float upsample_sigmoid(const float* __restrict__ src,
                                                  int x0, int x1, float wx, int y) {
  // jax.image.resize bilinear, half-pixel; edge weight renormalization == clamp
  float sy = 0.25f * (float)y - 0.375f;
  int y0 = (int)floorf(sy);
  float wy = sy - (float)y0;
  int y1 = y0 + 1;
  if (y0 < 0) y0 = 0;
  if (y1 > 63) y1 = 63;
  float a = src[y0 * 64 + x0] * (1.f - wx) + src[y0 * 64 + x1] * wx;
  float b = src[y1 * 64 + x0] * (1.f - wx) + src[y1 * 64 + x1] * wx;
  float v = a * (1.f - wy) + b * wy;
  return 1.f / (1.f + expf(-v));
}

// ---- cal samples: features + histogram + CDF + counting scatter + sum(sq) ----
__global__ __launch_bounds__(256) void k_cal(const float* __restrict__ feat,
                                             const int* __restrict__ gt,
                                             float* __restrict__ res,
                                             unsigned* __restrict__ cdf,
                                             unsigned short* __restrict__ grouped,
                                             float* __restrict__ cc) {
  __shared__ unsigned smem[16384];  // [0,HB): hist->counters; [16320..3] wave totals; [16324..7] cc partials
  const int n = blockIdx.x, tid = threadIdx.x;
  const int lane = tid & 63, wv = tid >> 6;
  for (int i = tid; i < HB; i += 256) smem[i] = 0;
  const float* src = feat + n * 4096;
  const int* gtn = gt + (size_t)n * NPIX;
  float* resn = res + (size_t)n * NPIX;
  float sx = 0.25f * (float)tid - 0.375f;
  int x0 = (int)floorf(sx);
  float wx = sx - (float)x0;
  int x1 = x0 + 1;
  if (x0 < 0) x0 = 0;
  if (x1 > 63) x1 = 63;
  __syncthreads();
  float sumsq = 0.f;
  for (int y = 0; y < 256; ++y) {
    float s = upsample_sigmoid(src, x0, x1, wx, y);
    int p = (y << 8) + tid;
    resn[p] = s;
    sumsq += s * s;
    if (gtn[p] > 0) atomicAdd(&smem[__float_as_uint(s) >> 16], 1u);
  }
  // cc partial (wave reduce, 4 partials via LDS)
  float ss = sumsq;
  #pragma unroll
  for (int off = 32; off; off >>= 1) ss += __shfl_xor(ss, off);
  if (lane == 0) smem[16324 + wv] = __float_as_uint(ss);
  __syncthreads();  // S1: hist + cc partials final
  if (tid == 0) {
    cc[n] = __uint_as_float(smem[16324]) + __uint_as_float(smem[16325]) +
            __uint_as_float(smem[16326]) + __uint_as_float(smem[16327]);
  }
  // exclusive scan of 16256 buckets: 64/thread chunks (threads 0..253), wave shfl scan of partials
  const int base = tid * 64;
  unsigned psum = 0;
  if (base < HB) {
    for (int j = 0; j < 64; ++j) psum += smem[base + ((j + tid) & 63)];  // rotated: conflict-free
  }
  unsigned inc = psum;
  #pragma unroll
  for (int off = 1; off < 64; off <<= 1) {
    unsigned v = __shfl_up(inc, off);
    if (lane >= off) inc += v;
  }
  if (lane == 63) smem[16320 + wv] = inc;
  __syncthreads();  // S2
  unsigned woff = 0;
  for (int w = 0; w < wv; ++w) woff += smem[16320 + w];
  unsigned run = woff + inc - psum;
  unsigned* cdfn = cdf + (size_t)n * CDF_STRIDE;
  if (base < HB) {
    for (int j = 0; j < 64; ++j) {
      unsigned hcnt = smem[base + j];
      cdfn[base + j] = run;
      smem[base + j] = run;  // becomes scatter counter
      run += hcnt;
    }
  }
  if (tid == 255) cdfn[HB] = woff + inc;  // total positives
  __syncthreads();  // S3: counters ready
  // phase B: counting scatter of low-16 bits (re-read res from L2 for bit-exact consistency)
  unsigned short* gn = grouped + (size_t)n * NPIX;
  for (int p = tid; p < NPIX; p += 256) {
    if (gtn[p] > 0) {
      unsigned bits = __float_as_uint(resn[p]);
      unsigned idx = atomicAdd(&smem[bits >> 16], 1u);
      gn[idx] = (unsigned short)(bits & 0xFFFFu);
    }
  }
}

// ---- test samples: features + sum(sq) ----
__global__ __launch_bounds__(256) void k_test(const float* __restrict__ feat,
                                              float* __restrict__ res,
                                              float* __restrict__ tt) {
  __shared__ float red[256];
  const int b = blockIdx.x, tid = threadIdx.x;
  const float* src = feat + b * 4096;
  float* resb = res + (size_t)b * NPIX;
  float sx = 0.25f * (float)tid - 0.375f;
  int x0 = (int)floorf(sx);
  float wx = sx - (float)x0;
  int x1 = x0 + 1;
  if (x0 < 0) x0 = 0;
  if (x1 > 63) x1 = 63;
  float sumsq = 0.f;
  for (int y = 0; y < 256; ++y) {
    float s = upsample_sigmoid(src, x0, x1, wx, y);
    resb[(y << 8) + tid] = s;
    sumsq += s * s;
  }
  red[tid] = sumsq;
  __syncthreads();
  for (int sd = 128; sd; sd >>= 1) {
    if (tid < sd) red[tid] += red[tid + sd];
    __syncthreads();
  }
  if (tid == 0) tt[b] = red[0];
}

// ---- G[b][n] = <tf_b, cf_n>, split-K by 8 ----
__global__ __launch_bounds__(256) void k_gemm(const float* __restrict__ tres,
                                              const float* __restrict__ cres,
                                              float* __restrict__ gpart) {
  __shared__ float tf[32][512];  // 64 KB
  const int tid = threadIdx.x;
  const int lane = tid & 63, wv = tid >> 6;
  const int n0 = blockIdx.x * 8 + wv * 2;  // wave handles cal rows n0, n0+1
  const int kbase = blockIdx.y * 8192;
  float acc0[32], acc1[32];
  #pragma unroll
  for (int b = 0; b < 32; ++b) { acc0[b] = 0.f; acc1[b] = 0.f; }
  for (int sc = 0; sc < 8192; sc += 512) {
    __syncthreads();
    #pragma unroll
    for (int r = 0; r < 16; ++r) {
      int f4 = (r << 8) + tid;
      int b = f4 >> 7, kk = (f4 & 127) << 2;
      *(float4*)&tf[b][kk] = *(const float4*)(tres + (size_t)b * NPIX + kbase + sc + kk);
    }
    __syncthreads();
    const float* c0 = cres + (size_t)n0 * NPIX + kbase + sc + 2 * lane;
    const float* c1 = c0 + NPIX;
    float2 cf0[4], cf1[4];
    #pragma unroll
    for (int i = 0; i < 4; ++i) {
      cf0[i] = *(const float2*)(c0 + (i << 7));
      cf1[i] = *(const float2*)(c1 + (i << 7));
    }
    #pragma unroll
    for (int i = 0; i < 4; ++i) {
      #pragma unroll
      for (int b = 0; b < 32; ++b) {
        float2 t2 = *(const float2*)&tf[b][2 * lane + (i << 7)];
        acc0[b] += t2.x * cf0[i].x;
        acc0[b] += t2.y * cf0[i].y;
        acc1[b] += t2.x * cf1[i].x;
        acc1[b] += t2.y * cf1[i].y;
      }
    }
  }
  float out0 = 0.f, out1 = 0.f;
  #pragma unroll
  for (int b = 0; b < 32; ++b) {
    float v0 = acc0[b], v1 = acc1[b];
    #pragma unroll
    for (int off = 32; off; off >>= 1) { v0 += __shfl_xor(v0, off); v1 += __shfl_xor(v1, off); }
    if (lane == b) { out0 = v0; out1 = v1; }
  }
  if (lane < 32) {
    float* gp = gpart + blockIdx.y * 8192 + lane * 256 + n0;
    gp[0] = out0;
    gp[1] = out1;
  }
}

// ---- Gaussian weights -> Q = w/(wsum*pos), wlast ----
__global__ __launch_bounds__(256) void k_weights(const float* __restrict__ gpart,
                                                 const float* __restrict__ cc,
                                                 const float* __restrict__ tt,
                                                 const unsigned* __restrict__ cdf,
                                                 float* __restrict__ Q,
                                                 float* __restrict__ wlast) {
  __shared__ float red[256];
  const int b = blockIdx.x, n = threadIdx.x;
  float g = 0.f;
  #pragma unroll
  for (int kc = 0; kc < 8; ++kc) g += gpart[kc * 8192 + b * 256 + n];
  float d2 = tt[b] + cc[n] - 2.f * g;
  float k = expf(-d2 * (1.f / 8192.f));  // exp(-d2/(2*64^2))
  red[n] = k;
  __syncthreads();
  for (int sd = 128; sd; sd >>= 1) {
    if (n < sd) red[n] += red[n + sd];
    __syncthreads();
  }
  float wsum = red[0] + 1.f;
  unsigned pos = cdf[(size_t)n * CDF_STRIDE + HB];
  float posf = (float)(pos ? pos : 1u);
  Q[b * 256 + n] = k / (wsum * posf);
  if (n == 0) wlast[b] = 1.f / wsum;
}

// ---- 50-iteration bisection per test sample ----
__global__ __launch_bounds__(512) void k_bisect(const unsigned* __restrict__ cdf,
                                                const unsigned short* __restrict__ grouped,
                                                const float* __restrict__ Q,
                                                const float* __restrict__ wlast,
                                                float* __restrict__ lam) {
  __shared__ float red[512];
  __shared__ float ctl[3];  // low, high, lam
  const int b = blockIdx.x, tid = threadIdx.x;
  const int n = tid >> 1, h = tid & 1;
  const float q = Q[b * 256 + n];
  const float wl = wlast[b];
  const unsigned* cn = cdf + (size_t)n * CDF_STRIDE;
  const unsigned short* gn = grouped + (size_t)n * NPIX;
  if (tid == 0) { ctl[0] = 0.f; ctl[1] = 1.f; }
  for (int it = 0; it < 50; ++it) {
    if (tid == 0) ctl[2] = 0.5f * (ctl[0] + ctl[1]);
    __syncthreads();
    const float lamv = ctl[2];
    const float t = 1.0f - lamv;
    const unsigned tb = __float_as_uint(t);
    const unsigned bu = tb >> 16;
    const unsigned lo16 = tb & 0xFFFFu;
    unsigned cnt;
    if (bu >= HB) {  // t == 1.0f: all positive scores (<1) count
      cnt = h ? 0u : cn[HB];
    } else {
      unsigned s0 = cn[bu], e0 = cn[bu + 1];
      cnt = h ? 0u : s0;
      for (unsigned j = s0 + h; j < e0; j += 2) cnt += (gn[j] < lo16) ? 1u : 0u;
    }
    red[tid] = q * (float)cnt;
    __syncthreads();
    if (tid < 64) {
      float v = red[tid];
      #pragma unroll
      for (int r = 64; r < 512; r += 64) v += red[tid + r];
      #pragma unroll
      for (int off = 32; off; off >>= 1) v += __shfl_xor(v, off);
      if (tid == 0) {
        float risk = v + wl;  // + wlast * B_CONST(=1)
        if (risk < ALPHA) ctl[1] = lamv; else ctl[0] = lamv;
      }
    }
    __syncthreads();
  }
  if (tid == 0) lam[b] = ctl[0];
}

// ---- final: size, test FNR ----
__global__ __launch_bounds__(256) void k_final(const float* __restrict__ tres,
                                               const int* __restrict__ tgt,
                                               const float* __restrict__ lam,
                                               float* __restrict__ out) {
  __shared__ int r0[256];
  __shared__ int r1[256];
  __shared__ int r2[256];
  const int b = blockIdx.x, tid = threadIdx.x;
  const float thr = 1.0f - lam[b];
  const float* rb = tres + (size_t)b * NPIX;
  const int* gb = tgt + (size_t)b * NPIX;
  int sz = 0, tp = 0, tpos = 0;
  for (int p = tid; p < NPIX; p += 256) {
    int pred = (rb[p] >= thr) ? 1 : 0;
    int tg = (gb[p] > 0) ? 1 : 0;
    sz += pred;
    tp += pred & tg;
    tpos += tg;
  }
  r0[tid] = sz; r1[tid] = tp; r2[tid] = tpos;
  __syncthreads();
  for (int sd = 128; sd; sd >>= 1) {
    if (tid < sd) { r0[tid] += r0[tid + sd]; r1[tid] += r1[tid + sd]; r2[tid] += r2[tid + sd]; }
    __syncthreads();
  }
  if (tid == 0) {
    float tposf = (float)(r2[0] > 0 ? r2[0] : 1);
    out[b] = 1.f - (float)r1[0] / tposf;   // fnr_test
    out[32 + b] = lam[b];                  // lambda
    out[64 + b] = (float)r0[0];            // size
  }
}

extern "C" void kernel_launch(void* const* d_in, const int* in_sizes, int n_in,
                              void* d_out, int out_size, void* d_ws, size_t ws_size,
                              hipStream_t stream) {
  const float* cal_feat = (const float*)d_in[0];
  const float* test_feat = (const float*)d_in[1];
  const int* cal_gt = (const int*)d_in[2];
  const int* test_gt = (const int*)d_in[3];
  float* out = (float*)d_out;
  char* ws = (char*)d_ws;

  float* cal_res = (float*)(ws + OFF_CALRES);
  float* test_res = (float*)(ws + OFF_TESTRES);
  unsigned short* grouped = (unsigned short*)(ws + OFF_GROUPED);
  unsigned* cdf = (unsigned*)(ws + OFF_CDF);
  float* gpart = (float*)(ws + OFF_GPART);
  float* cc = (float*)(ws + OFF_CC);
  float* tt = (float*)(ws + OFF_TT);
  float* Q = (float*)(ws + OFF_Q);
  float* wlast = (float*)(ws + OFF_WLAST);
  float* lam = (float*)(ws + OFF_LAM);

  k_cal<<<dim3(256), dim3(256), 0, stream>>>(cal_feat, cal_gt, cal_res, cdf, grouped, cc);
  k_test<<<dim3(32), dim3(256), 0, stream>>>(test_feat, test_res, tt);
  k_gemm<<<dim3(32, 8), dim3(256), 0, stream>>>(test_res, cal_res, gpart);
  k_weights<<<dim3(32), dim3(256), 0, stream>>>(gpart, cc, tt, cdf, Q, wlast);
  k_bisect<<<dim3(32), dim3(512), 0, stream>>>(cdf, grouped, Q, wlast, lam);
  k_final<<<dim3(32), dim3(256), 0, stream>>>(test_res, test_gt, lam, out);
}

// Round 2
// 602.652 us; speedup vs baseline: 1.5913x; 1.5913x over previous
//
#include <hip/hip_runtime.h>

// RandomlyLocalizedConformalRiskControl on MI355X.
// ws layout (bytes), total ~120.2 MB:
//   cal_res  f32 [256][65536]            @ 0          (64 MB)
//   test_res f32 [32][65536]             @ 67108864   (8 MB)
//   grouped  u16 [256][65536]            @ 75497472   (32 MB)   low-16 bits of score, grouped by hi-16 bucket
//   cdf      u32 [256][CDF_STRIDE]       @ 109051904  (16 MB)   exclusive CDF over 16256 hi-16 buckets; [HB]=pos
//   gpart    f32 [8][32][256]            @ 125714432
//   cc f32[256], tt f32[32], thr f32[32], lam f32[32]

#define NPIX 65536
#define HB 16256            // buckets = float_bits >> 16 for scores in (0, 1.0]
#define CDF_STRIDE 16272
#define ALPHA 0.1f

#define OFF_CALRES   0
#define OFF_TESTRES  67108864u
#define OFF_GROUPED  75497472u
#define OFF_CDF      109051904u
#define OFF_GPART    125714432u
#define OFF_CC       125976576u
#define OFF_TT       125977600u
#define OFF_THR      125977728u
#define OFF_LAM      125977984u

__device__ __forceinline__ float upsample_sigmoid(const float* __restrict__ src,
                                                  int x0, int x1, float wx, int y) {
  // jax.image.resize bilinear, half-pixel; edge weight renormalization == clamp
  float sy = 0.25f * (float)y - 0.375f;
  int y0 = (int)floorf(sy);
  float wy = sy - (float)y0;
  int y1 = y0 + 1;
  if (y0 < 0) y0 = 0;
  if (y1 > 63) y1 = 63;
  float a = src[y0 * 64 + x0] * (1.f - wx) + src[y0 * 64 + x1] * wx;
  float b = src[y1 * 64 + x0] * (1.f - wx) + src[y1 * 64 + x1] * wx;
  float v = a * (1.f - wy) + b * wy;
  return 1.f / (1.f + expf(-v));
}

// ---- cal samples: features + histogram + CDF + counting scatter + sum(sq) ----
__global__ __launch_bounds__(256) void k_cal(const float* __restrict__ feat,
                                             const int* __restrict__ gt,
                                             float* __restrict__ res,
                                             unsigned* __restrict__ cdf,
                                             unsigned short* __restrict__ grouped,
                                             float* __restrict__ cc) {
  __shared__ unsigned smem[16384];  // [0,HB): hist->counters; [16320..3] wave totals; [16324..7] cc partials
  const int n = blockIdx.x, tid = threadIdx.x;
  const int lane = tid & 63, wv = tid >> 6;
  for (int i = tid; i < HB; i += 256) smem[i] = 0;
  const float* src = feat + n * 4096;
  const int* gtn = gt + (size_t)n * NPIX;
  float* resn = res + (size_t)n * NPIX;
  float sx = 0.25f * (float)tid - 0.375f;
  int x0 = (int)floorf(sx);
  float wx = sx - (float)x0;
  int x1 = x0 + 1;
  if (x0 < 0) x0 = 0;
  if (x1 > 63) x1 = 63;
  __syncthreads();
  float sumsq = 0.f;
  for (int y = 0; y < 256; ++y) {
    float s = upsample_sigmoid(src, x0, x1, wx, y);
    int p = (y << 8) + tid;
    resn[p] = s;
    sumsq += s * s;
    if (gtn[p] > 0) atomicAdd(&smem[__float_as_uint(s) >> 16], 1u);
  }
  // cc partial (wave reduce, 4 partials via LDS)
  float ss = sumsq;
  #pragma unroll
  for (int off = 32; off; off >>= 1) ss += __shfl_xor(ss, off);
  if (lane == 0) smem[16324 + wv] = __float_as_uint(ss);
  __syncthreads();  // S1: hist + cc partials final
  if (tid == 0) {
    cc[n] = __uint_as_float(smem[16324]) + __uint_as_float(smem[16325]) +
            __uint_as_float(smem[16326]) + __uint_as_float(smem[16327]);
  }
  // exclusive scan of 16256 buckets: 64/thread chunks (threads 0..253), wave shfl scan of partials
  const int base = tid * 64;
  unsigned psum = 0;
  if (base < HB) {
    for (int j = 0; j < 64; ++j) psum += smem[base + ((j + tid) & 63)];  // rotated: conflict-free
  }
  unsigned inc = psum;
  #pragma unroll
  for (int off = 1; off < 64; off <<= 1) {
    unsigned v = __shfl_up(inc, off);
    if (lane >= off) inc += v;
  }
  if (lane == 63) smem[16320 + wv] = inc;
  __syncthreads();  // S2
  unsigned woff = 0;
  for (int w = 0; w < wv; ++w) woff += smem[16320 + w];
  unsigned run = woff + inc - psum;
  unsigned* cdfn = cdf + (size_t)n * CDF_STRIDE;
  if (base < HB) {
    for (int j = 0; j < 64; ++j) {
      unsigned hcnt = smem[base + j];
      cdfn[base + j] = run;
      smem[base + j] = run;  // becomes scatter counter
      run += hcnt;
    }
  }
  if (tid == 255) cdfn[HB] = woff + inc;  // total positives
  __syncthreads();  // S3: counters ready
  // phase B: counting scatter of low-16 bits (re-read res from L2 for bit-exact consistency)
  unsigned short* gn = grouped + (size_t)n * NPIX;
  for (int p = tid; p < NPIX; p += 256) {
    if (gtn[p] > 0) {
      unsigned bits = __float_as_uint(resn[p]);
      unsigned idx = atomicAdd(&smem[bits >> 16], 1u);
      gn[idx] = (unsigned short)(bits & 0xFFFFu);
    }
  }
}

// ---- test samples: features + sum(sq) ----
__global__ __launch_bounds__(256) void k_test(const float* __restrict__ feat,
                                              float* __restrict__ res,
                                              float* __restrict__ tt) {
  __shared__ float red[256];
  const int b = blockIdx.x, tid = threadIdx.x;
  const float* src = feat + b * 4096;
  float* resb = res + (size_t)b * NPIX;
  float sx = 0.25f * (float)tid - 0.375f;
  int x0 = (int)floorf(sx);
  float wx = sx - (float)x0;
  int x1 = x0 + 1;
  if (x0 < 0) x0 = 0;
  if (x1 > 63) x1 = 63;
  float sumsq = 0.f;
  for (int y = 0; y < 256; ++y) {
    float s = upsample_sigmoid(src, x0, x1, wx, y);
    resb[(y << 8) + tid] = s;
    sumsq += s * s;
  }
  red[tid] = sumsq;
  __syncthreads();
  for (int sd = 128; sd; sd >>= 1) {
    if (tid < sd) red[tid] += red[tid + sd];
    __syncthreads();
  }
  if (tid == 0) tt[b] = red[0];
}

// ---- G[b][n] = <tf_b, cf_n>, split-K by 8 ----
__global__ __launch_bounds__(256) void k_gemm(const float* __restrict__ tres,
                                              const float* __restrict__ cres,
                                              float* __restrict__ gpart) {
  __shared__ float tf[32][512];  // 64 KB
  const int tid = threadIdx.x;
  const int lane = tid & 63, wv = tid >> 6;
  const int n0 = blockIdx.x * 8 + wv * 2;  // wave handles cal rows n0, n0+1
  const int kbase = blockIdx.y * 8192;
  float acc0[32], acc1[32];
  #pragma unroll
  for (int b = 0; b < 32; ++b) { acc0[b] = 0.f; acc1[b] = 0.f; }
  for (int sc = 0; sc < 8192; sc += 512) {
    __syncthreads();
    #pragma unroll
    for (int r = 0; r < 16; ++r) {
      int f4 = (r << 8) + tid;
      int b = f4 >> 7, kk = (f4 & 127) << 2;
      *(float4*)&tf[b][kk] = *(const float4*)(tres + (size_t)b * NPIX + kbase + sc + kk);
    }
    __syncthreads();
    const float* c0 = cres + (size_t)n0 * NPIX + kbase + sc + 2 * lane;
    const float* c1 = c0 + NPIX;
    float2 cf0[4], cf1[4];
    #pragma unroll
    for (int i = 0; i < 4; ++i) {
      cf0[i] = *(const float2*)(c0 + (i << 7));
      cf1[i] = *(const float2*)(c1 + (i << 7));
    }
    #pragma unroll
    for (int i = 0; i < 4; ++i) {
      #pragma unroll
      for (int b = 0; b < 32; ++b) {
        float2 t2 = *(const float2*)&tf[b][2 * lane + (i << 7)];
        acc0[b] += t2.x * cf0[i].x;
        acc0[b] += t2.y * cf0[i].y;
        acc1[b] += t2.x * cf1[i].x;
        acc1[b] += t2.y * cf1[i].y;
      }
    }
  }
  float out0 = 0.f, out1 = 0.f;
  #pragma unroll
  for (int b = 0; b < 32; ++b) {
    float v0 = acc0[b], v1 = acc1[b];
    #pragma unroll
    for (int off = 32; off; off >>= 1) { v0 += __shfl_xor(v0, off); v1 += __shfl_xor(v1, off); }
    if (lane == b) { out0 = v0; out1 = v1; }
  }
  if (lane < 32) {
    float* gp = gpart + blockIdx.y * 8192 + lane * 256 + n0;
    gp[0] = out0;
    gp[1] = out1;
  }
}

// ---- weights + direct weighted-quantile (replaces 50-iter bisection) ----
// risk(lam) is monotone, so final low == crossing score u* = inf{t : sum_n q_n*cnt_n(t) >= R},
// R = ALPHA - wlast. Since cdf_n is an exclusive CDF, S(B) = sum_n q_n*cdf_n[B] is evaluable
// for any hi-16 bucket B in one 256-wide reduce -> 14-step binary search; then one gather pass
// builds a 4096-bin weighted lo-16 histogram of the crossing bucket -> t* to 28 bits.
__global__ __launch_bounds__(512) void k_quant(const float* __restrict__ gpart,
                                               const float* __restrict__ cc,
                                               const float* __restrict__ tt,
                                               const unsigned* __restrict__ cdf,
                                               const unsigned short* __restrict__ grouped,
                                               float* __restrict__ lam,
                                               float* __restrict__ thr) {
  __shared__ float qs[256];
  __shared__ float bins[4096];
  __shared__ float red[8];
  __shared__ float bc[2];      // [0]=wsum, [1]=S(mid) broadcast
  __shared__ unsigned sBin;
  const int b = blockIdx.x, tid = threadIdx.x;
  const int lane = tid & 63, wv = tid >> 6;

  for (int i = tid; i < 4096; i += 512) bins[i] = 0.f;
  if (tid == 0) sBin = 0xFFFFFFFFu;

  // ---- weights: k_n = exp(-d2/8192) ----
  float k = 0.f;
  if (tid < 256) {
    float g = 0.f;
    #pragma unroll
    for (int kc = 0; kc < 8; ++kc) g += gpart[kc * 8192 + b * 256 + tid];
    float d2 = tt[b] + cc[tid] - 2.f * g;
    k = expf(-d2 * (1.f / 8192.f));
  }
  float v = k;
  #pragma unroll
  for (int off = 32; off; off >>= 1) v += __shfl_xor(v, off);
  if (lane == 0) red[wv] = v;
  __syncthreads();
  if (tid == 0) {
    float ws = 1.f;
    for (int w = 0; w < 8; ++w) ws += red[w];
    bc[0] = ws;
  }
  __syncthreads();
  const float wsum = bc[0];
  const float wlast = 1.f / wsum;
  const float R = ALPHA - wlast;
  if (R <= 0.f) {  // risk >= alpha for every lam -> low -> 1.0f, thr 0 (predict all)
    if (tid == 0) { lam[b] = 1.0f; thr[b] = 0.0f; }
    return;
  }
  if (tid < 256) {
    unsigned pos = cdf[(size_t)tid * CDF_STRIDE + HB];
    qs[tid] = k / (wsum * (float)(pos ? pos : 1u));
  }
  __syncthreads();

  // ---- 14-step binary search over hi-16 buckets: invariant S(lo) < R <= S(hi) ----
  int lo = 0, hi = HB;
  float baseS = 0.f;
  for (int it = 0; it < 14; ++it) {
    int mid = (lo + hi) >> 1;
    float p = 0.f;
    if (tid < 256) p = qs[tid] * (float)cdf[(size_t)tid * CDF_STRIDE + mid];
    float r = p;
    #pragma unroll
    for (int off = 32; off; off >>= 1) r += __shfl_xor(r, off);
    if (lane == 0) red[wv] = r;
    __syncthreads();
    if (tid == 0) {
      float s = 0.f;
      for (int w = 0; w < 8; ++w) s += red[w];
      bc[1] = s;
    }
    __syncthreads();
    float S = bc[1];
    if (S < R) { lo = mid; baseS = S; } else { hi = mid; }
  }
  const int B = lo;  // crossing bucket; baseS = weighted count below it

  // ---- gather bucket B members into 4096-bin weighted histogram of lo16>>4 ----
  {
    const int n = tid >> 1;
    const float q = qs[n];
    const unsigned* cn = cdf + (size_t)n * CDF_STRIDE;
    const unsigned short* gn = grouped + (size_t)n * NPIX;
    unsigned e0 = cn[B + 1];
    for (unsigned j = cn[B] + (tid & 1); j < e0; j += 2)
      atomicAdd(&bins[gn[j] >> 4], q);
  }
  __syncthreads();

  // ---- wave 0: scan 4096 bins, find crossing bin ----
  if (wv == 0) {
    float s = 0.f;
    for (int j = 0; j < 64; ++j) s += bins[lane * 64 + j];
    float inc = s;
    #pragma unroll
    for (int off = 1; off < 64; off <<= 1) {
      float u = __shfl_up(inc, off);
      if (lane >= off) inc += u;
    }
    float pre = inc - s;
    bool hit = (baseS + pre < R) && (baseS + inc >= R);
    unsigned long long m = __ballot(hit);
    int ow = m ? (__ffsll((unsigned long long)m) - 1) : -1;
    if (lane == ow) {
      float run = baseS + pre;
      unsigned bin = (unsigned)lane * 64 + 63;
      for (int j = 0; j < 64; ++j) {
        float bv = bins[lane * 64 + j];
        if (run + bv >= R) { bin = (unsigned)lane * 64 + j; break; }
        run += bv;
      }
      sBin = bin;
    }
    if (m == 0 && lane == 0) sBin = 4095u;  // f32-rounding fallback (unreachable in practice)
  }
  __syncthreads();
  if (tid == 0) {
    unsigned tb = ((unsigned)B << 16) | (sBin << 4);
    lam[b] = 1.0f - __uint_as_float(tb | 0x8u);     // mid-bin representative
    thr[b] = __uint_as_float((tb | 0xFu) + 1u);     // strictly above bin top: pred = res > u*
  }
}

// ---- final: size, test FNR ----
__global__ __launch_bounds__(256) void k_final(const float* __restrict__ tres,
                                               const int* __restrict__ tgt,
                                               const float* __restrict__ lam,
                                               const float* __restrict__ thr,
                                               float* __restrict__ out) {
  __shared__ int r0[256];
  __shared__ int r1[256];
  __shared__ int r2[256];
  const int b = blockIdx.x, tid = threadIdx.x;
  const float th = thr[b];
  const float* rb = tres + (size_t)b * NPIX;
  const int* gb = tgt + (size_t)b * NPIX;
  int sz = 0, tp = 0, tpos = 0;
  for (int p = tid; p < NPIX; p += 256) {
    int pred = (rb[p] >= th) ? 1 : 0;
    int tg = (gb[p] > 0) ? 1 : 0;
    sz += pred;
    tp += pred & tg;
    tpos += tg;
  }
  r0[tid] = sz; r1[tid] = tp; r2[tid] = tpos;
  __syncthreads();
  for (int sd = 128; sd; sd >>= 1) {
    if (tid < sd) { r0[tid] += r0[tid + sd]; r1[tid] += r1[tid + sd]; r2[tid] += r2[tid + sd]; }
    __syncthreads();
  }
  if (tid == 0) {
    float tposf = (float)(r2[0] > 0 ? r2[0] : 1);
    out[b] = 1.f - (float)r1[0] / tposf;   // fnr_test
    out[32 + b] = lam[b];                  // lambda
    out[64 + b] = (float)r0[0];            // size
  }
}

extern "C" void kernel_launch(void* const* d_in, const int* in_sizes, int n_in,
                              void* d_out, int out_size, void* d_ws, size_t ws_size,
                              hipStream_t stream) {
  const float* cal_feat = (const float*)d_in[0];
  const float* test_feat = (const float*)d_in[1];
  const int* cal_gt = (const int*)d_in[2];
  const int* test_gt = (const int*)d_in[3];
  float* out = (float*)d_out;
  char* ws = (char*)d_ws;

  float* cal_res = (float*)(ws + OFF_CALRES);
  float* test_res = (float*)(ws + OFF_TESTRES);
  unsigned short* grouped = (unsigned short*)(ws + OFF_GROUPED);
  unsigned* cdf = (unsigned*)(ws + OFF_CDF);
  float* gpart = (float*)(ws + OFF_GPART);
  float* cc = (float*)(ws + OFF_CC);
  float* tt = (float*)(ws + OFF_TT);
  float* thr = (float*)(ws + OFF_THR);
  float* lam = (float*)(ws + OFF_LAM);

  k_cal<<<dim3(256), dim3(256), 0, stream>>>(cal_feat, cal_gt, cal_res, cdf, grouped, cc);
  k_test<<<dim3(32), dim3(256), 0, stream>>>(test_feat, test_res, tt);
  k_gemm<<<dim3(32, 8), dim3(256), 0, stream>>>(test_res, cal_res, gpart);
  k_quant<<<dim3(32), dim3(512), 0, stream>>>(gpart, cc, tt, cdf, grouped, lam, thr);
  k_final<<<dim3(32), dim3(256), 0, stream>>>(test_res, test_gt, lam, thr, out);
}

// Round 3
// 559.793 us; speedup vs baseline: 1.7132x; 1.0766x over previous
//
#include <hip/hip_runtime.h>

// RandomlyLocalizedConformalRiskControl on MI355X.
// ws layout (bytes), max used ~125.75 MB (round-1 high-water was 126.01 MB):
//   cal_res  f32 [256][65536]            @ 0          (64 MB)
//   test_res f32 [32][65536]             @ 67108864   (8 MB)
//   grouped  u16 [256][65536]            @ 75497472   (32 MB)   low-16 bits of score, grouped by hi-16 bucket
//   cdf      u32 [256][CDF_STRIDE]       @ 109051904  (16 MB)   exclusive CDF over 16256 hi-16 buckets; [HB]=pos
//   G        f32 [32][256]               @ 125714432  (32 KB)   dot products, atomic split-K accum
//   cc f32[256], tt f32[32], thr f32[32], lam f32[32]

#define NPIX 65536
#define HB 16256            // buckets = float_bits >> 16 for scores in (0, 1.0]
#define CDF_STRIDE 16272
#define ALPHA 0.1f

#define OFF_CALRES   0
#define OFF_TESTRES  67108864u
#define OFF_GROUPED  75497472u
#define OFF_CDF      109051904u
#define OFF_G        125714432u
#define OFF_CC       125747200u
#define OFF_TT       125748224u
#define OFF_THR      125748352u
#define OFF_LAM      125748480u

// ---- cal samples: features + histogram + CDF + counting scatter + sum(sq) ----
// 1024 threads (4 waves/SIMD) so global-load latency and LDS-atomic serialization overlap.
__global__ __launch_bounds__(1024, 4) void k_cal(const float* __restrict__ feat,
                                                 const int* __restrict__ gt,
                                                 float* __restrict__ res,
                                                 unsigned* __restrict__ cdf,
                                                 unsigned short* __restrict__ grouped,
                                                 float* __restrict__ cc) {
  __shared__ unsigned smem[16384];  // [0,HB): hist->counters; [16320..3] wave-scan totals; [16336..51] cc partials
  __shared__ float sfeat[4096];
  const int n = blockIdx.x, tid = threadIdx.x;
  const int lane = tid & 63, wv = tid >> 6;
  for (int i = tid; i < HB; i += 1024) smem[i] = 0;
  for (int i = tid; i < 4096; i += 1024) sfeat[i] = feat[n * 4096 + i];
  const int* gtn = gt + (size_t)n * NPIX;
  float* resn = res + (size_t)n * NPIX;
  const int x = tid & 255;
  const int yq = tid >> 8;  // 0..3
  float sx = 0.25f * (float)x - 0.375f;
  int x0 = (int)floorf(sx);
  float wx = sx - (float)x0;
  int x1 = x0 + 1;
  if (x0 < 0) x0 = 0;
  if (x1 > 63) x1 = 63;
  __syncthreads();
  float sumsq = 0.f;
  for (int it = 0; it < 64; ++it) {
    int y = it * 4 + yq;
    float sy = 0.25f * (float)y - 0.375f;
    int y0 = (int)floorf(sy);
    float wy = sy - (float)y0;
    int y1 = y0 + 1;
    if (y0 < 0) y0 = 0;
    if (y1 > 63) y1 = 63;
    float a = sfeat[y0 * 64 + x0] * (1.f - wx) + sfeat[y0 * 64 + x1] * wx;
    float b = sfeat[y1 * 64 + x0] * (1.f - wx) + sfeat[y1 * 64 + x1] * wx;
    float v = a * (1.f - wy) + b * wy;
    float s = 1.f / (1.f + __expf(-v));
    int p = (y << 8) + x;
    resn[p] = s;
    sumsq += s * s;
    if (gtn[p] > 0) atomicAdd(&smem[__float_as_uint(s) >> 16], 1u);
  }
  // cc partials (16 waves)
  float ss = sumsq;
  #pragma unroll
  for (int off = 32; off; off >>= 1) ss += __shfl_xor(ss, off);
  if (lane == 0) smem[16336 + wv] = __float_as_uint(ss);
  __syncthreads();  // S1: hist + cc partials final
  if (tid == 0) {
    float c = 0.f;
    for (int w = 0; w < 16; ++w) c += __uint_as_float(smem[16336 + w]);
    cc[n] = c;
  }
  // exclusive scan of 16256 buckets on threads 0..255 (64/thread), wave shfl scan of partials
  unsigned* cdfn = cdf + (size_t)n * CDF_STRIDE;
  if (tid < 256) {
    const int base = tid * 64;
    unsigned psum = 0;
    if (base < HB) {
      for (int j = 0; j < 64; ++j) psum += smem[base + ((j + tid) & 63)];  // rotated: conflict-free
    }
    unsigned inc = psum;
    #pragma unroll
    for (int off = 1; off < 64; off <<= 1) {
      unsigned v = __shfl_up(inc, off);
      if (lane >= off) inc += v;
    }
    if (lane == 63) smem[16320 + wv] = inc;
  }
  __syncthreads();  // S2
  if (tid < 256) {
    const int base = tid * 64;
    unsigned psum = 0;
    if (base < HB) {
      for (int j = 0; j < 64; ++j) psum += smem[base + ((j + tid) & 63)];
    }
    unsigned inc = psum;
    #pragma unroll
    for (int off = 1; off < 64; off <<= 1) {
      unsigned v = __shfl_up(inc, off);
      if (lane >= off) inc += v;
    }
    unsigned woff = 0;
    for (int w = 0; w < wv; ++w) woff += smem[16320 + w];
    unsigned run = woff + inc - psum;
    if (base < HB) {
      for (int j = 0; j < 64; ++j) {
        unsigned hcnt = smem[base + j];
        cdfn[base + j] = run;
        smem[base + j] = run;  // becomes scatter counter
        run += hcnt;
      }
    }
    if (tid == 255) cdfn[HB] = woff + inc;  // total positives
  }
  __syncthreads();  // S3: counters ready (smem[0..HB) now scatter counters)
  // phase B: counting scatter of low-16 bits (re-read res from L1/L2 for bit-exact consistency)
  unsigned short* gn = grouped + (size_t)n * NPIX;
  for (int p = tid; p < NPIX; p += 1024) {
    if (gtn[p] > 0) {
      unsigned bits = __float_as_uint(resn[p]);
      unsigned idx = atomicAdd(&smem[bits >> 16], 1u);
      gn[idx] = (unsigned short)(bits & 0xFFFFu);
    }
  }
}

// ---- test samples: features + sum(sq); also zero-inits G for k_gemm's atomic split-K ----
__global__ __launch_bounds__(1024, 4) void k_test(const float* __restrict__ feat,
                                                  float* __restrict__ res,
                                                  float* __restrict__ tt,
                                                  float* __restrict__ G) {
  __shared__ float sfeat[4096];
  __shared__ float red[16];
  const int b = blockIdx.x, tid = threadIdx.x;
  const int lane = tid & 63, wv = tid >> 6;
  for (int i = tid; i < 4096; i += 1024) sfeat[i] = feat[b * 4096 + i];
  if (tid < 256) G[b * 256 + tid] = 0.f;
  float* resb = res + (size_t)b * NPIX;
  const int x = tid & 255;
  const int yq = tid >> 8;
  float sx = 0.25f * (float)x - 0.375f;
  int x0 = (int)floorf(sx);
  float wx = sx - (float)x0;
  int x1 = x0 + 1;
  if (x0 < 0) x0 = 0;
  if (x1 > 63) x1 = 63;
  __syncthreads();
  float sumsq = 0.f;
  for (int it = 0; it < 64; ++it) {
    int y = it * 4 + yq;
    float sy = 0.25f * (float)y - 0.375f;
    int y0 = (int)floorf(sy);
    float wy = sy - (float)y0;
    int y1 = y0 + 1;
    if (y0 < 0) y0 = 0;
    if (y1 > 63) y1 = 63;
    float a = sfeat[y0 * 64 + x0] * (1.f - wx) + sfeat[y0 * 64 + x1] * wx;
    float bb = sfeat[y1 * 64 + x0] * (1.f - wx) + sfeat[y1 * 64 + x1] * wx;
    float v = a * (1.f - wy) + bb * wy;
    float s = 1.f / (1.f + __expf(-v));
    resb[(y << 8) + x] = s;
    sumsq += s * s;
  }
  #pragma unroll
  for (int off = 32; off; off >>= 1) sumsq += __shfl_xor(sumsq, off);
  if (lane == 0) red[wv] = sumsq;
  __syncthreads();
  if (tid == 0) {
    float t = 0.f;
    for (int w = 0; w < 16; ++w) t += red[w];
    tt[b] = t;
  }
}

// ---- G[b][n] += <tf_b, cf_n> over this block's 2048-wide K-slice (32-way split-K) ----
__global__ __launch_bounds__(256, 4) void k_gemm(const float* __restrict__ tres,
                                                 const float* __restrict__ cres,
                                                 float* __restrict__ G) {
  __shared__ float tf[32][256];  // 32 KB -> 4 blocks/CU
  const int tid = threadIdx.x;
  const int lane = tid & 63, wv = tid >> 6;
  const int n0 = blockIdx.x * 8 + wv * 2;  // wave handles cal rows n0, n0+1
  const int kbase = blockIdx.y * 2048;
  float acc0[32], acc1[32];
  #pragma unroll
  for (int b = 0; b < 32; ++b) { acc0[b] = 0.f; acc1[b] = 0.f; }
  for (int sc = 0; sc < 2048; sc += 256) {
    __syncthreads();
    #pragma unroll
    for (int r = 0; r < 8; ++r) {
      int f4 = (r << 8) + tid;
      int b = f4 >> 6, kk = (f4 & 63) << 2;
      *(float4*)&tf[b][kk] = *(const float4*)(tres + (size_t)b * NPIX + kbase + sc + kk);
    }
    __syncthreads();
    const float* c0 = cres + (size_t)n0 * NPIX + kbase + sc + 2 * lane;
    const float* c1 = c0 + NPIX;
    float2 cf0[2], cf1[2];
    #pragma unroll
    for (int i = 0; i < 2; ++i) {
      cf0[i] = *(const float2*)(c0 + (i << 7));
      cf1[i] = *(const float2*)(c1 + (i << 7));
    }
    #pragma unroll
    for (int i = 0; i < 2; ++i) {
      #pragma unroll
      for (int b = 0; b < 32; ++b) {
        float2 t2 = *(const float2*)&tf[b][2 * lane + (i << 7)];
        acc0[b] += t2.x * cf0[i].x;
        acc0[b] += t2.y * cf0[i].y;
        acc1[b] += t2.x * cf1[i].x;
        acc1[b] += t2.y * cf1[i].y;
      }
    }
  }
  float out0 = 0.f, out1 = 0.f;
  #pragma unroll
  for (int b = 0; b < 32; ++b) {
    float v0 = acc0[b], v1 = acc1[b];
    #pragma unroll
    for (int off = 32; off; off >>= 1) { v0 += __shfl_xor(v0, off); v1 += __shfl_xor(v1, off); }
    if (lane == b) { out0 = v0; out1 = v1; }
  }
  if (lane < 32) {
    atomicAdd(&G[lane * 256 + n0], out0);
    atomicAdd(&G[lane * 256 + n0 + 1], out1);
  }
}

// ---- weights + direct weighted-quantile ----
// u* = inf{t : sum_n q_n*cnt_n(t) >= R}, R = ALPHA - wlast; 14-step binary search over the
// hi-16 bucket CDFs, then a 4096-bin weighted lo-16 histogram of the crossing bucket.
__global__ __launch_bounds__(512) void k_quant(const float* __restrict__ G,
                                               const float* __restrict__ cc,
                                               const float* __restrict__ tt,
                                               const unsigned* __restrict__ cdf,
                                               const unsigned short* __restrict__ grouped,
                                               float* __restrict__ lam,
                                               float* __restrict__ thr) {
  __shared__ float qs[256];
  __shared__ float bins[4096];
  __shared__ float red[8];
  __shared__ float bc[2];      // [0]=wsum, [1]=S(mid) broadcast
  __shared__ unsigned sBin;
  const int b = blockIdx.x, tid = threadIdx.x;
  const int lane = tid & 63, wv = tid >> 6;

  for (int i = tid; i < 4096; i += 512) bins[i] = 0.f;
  if (tid == 0) sBin = 0xFFFFFFFFu;

  // ---- weights: k_n = exp(-d2/8192) ----
  float k = 0.f;
  if (tid < 256) {
    float g = G[b * 256 + tid];
    float d2 = tt[b] + cc[tid] - 2.f * g;
    k = expf(-d2 * (1.f / 8192.f));
  }
  float v = k;
  #pragma unroll
  for (int off = 32; off; off >>= 1) v += __shfl_xor(v, off);
  if (lane == 0) red[wv] = v;
  __syncthreads();
  if (tid == 0) {
    float ws = 1.f;
    for (int w = 0; w < 8; ++w) ws += red[w];
    bc[0] = ws;
  }
  __syncthreads();
  const float wsum = bc[0];
  const float wlast = 1.f / wsum;
  const float R = ALPHA - wlast;
  if (R <= 0.f) {  // risk >= alpha for every lam -> low -> 1.0f, thr 0 (predict all)
    if (tid == 0) { lam[b] = 1.0f; thr[b] = 0.0f; }
    return;
  }
  if (tid < 256) {
    unsigned pos = cdf[(size_t)tid * CDF_STRIDE + HB];
    qs[tid] = k / (wsum * (float)(pos ? pos : 1u));
  }
  __syncthreads();

  // ---- 14-step binary search over hi-16 buckets: invariant S(lo) < R <= S(hi) ----
  int lo = 0, hi = HB;
  float baseS = 0.f;
  for (int it = 0; it < 14; ++it) {
    int mid = (lo + hi) >> 1;
    float p = 0.f;
    if (tid < 256) p = qs[tid] * (float)cdf[(size_t)tid * CDF_STRIDE + mid];
    float r = p;
    #pragma unroll
    for (int off = 32; off; off >>= 1) r += __shfl_xor(r, off);
    if (lane == 0) red[wv] = r;
    __syncthreads();
    if (tid == 0) {
      float s = 0.f;
      for (int w = 0; w < 8; ++w) s += red[w];
      bc[1] = s;
    }
    __syncthreads();
    float S = bc[1];
    if (S < R) { lo = mid; baseS = S; } else { hi = mid; }
  }
  const int B = lo;  // crossing bucket; baseS = weighted count below it

  // ---- gather bucket B members into 4096-bin weighted histogram of lo16>>4 ----
  {
    const int n = tid >> 1;
    const float q = qs[n];
    const unsigned* cn = cdf + (size_t)n * CDF_STRIDE;
    const unsigned short* gn = grouped + (size_t)n * NPIX;
    unsigned e0 = cn[B + 1];
    for (unsigned j = cn[B] + (tid & 1); j < e0; j += 2)
      atomicAdd(&bins[gn[j] >> 4], q);
  }
  __syncthreads();

  // ---- wave 0: scan 4096 bins, find crossing bin ----
  if (wv == 0) {
    float s = 0.f;
    for (int j = 0; j < 64; ++j) s += bins[lane * 64 + j];
    float inc = s;
    #pragma unroll
    for (int off = 1; off < 64; off <<= 1) {
      float u = __shfl_up(inc, off);
      if (lane >= off) inc += u;
    }
    float pre = inc - s;
    bool hit = (baseS + pre < R) && (baseS + inc >= R);
    unsigned long long m = __ballot(hit);
    int ow = m ? (__ffsll((unsigned long long)m) - 1) : -1;
    if (lane == ow) {
      float run = baseS + pre;
      unsigned bin = (unsigned)lane * 64 + 63;
      for (int j = 0; j < 64; ++j) {
        float bv = bins[lane * 64 + j];
        if (run + bv >= R) { bin = (unsigned)lane * 64 + j; break; }
        run += bv;
      }
      sBin = bin;
    }
    if (m == 0 && lane == 0) sBin = 4095u;  // f32-rounding fallback (unreachable in practice)
  }
  __syncthreads();
  if (tid == 0) {
    unsigned tb = ((unsigned)B << 16) | (sBin << 4);
    lam[b] = 1.0f - __uint_as_float(tb | 0x8u);     // mid-bin representative
    thr[b] = __uint_as_float((tb | 0xFu) + 1u);     // strictly above bin top: pred = res > u*
  }
}

// ---- final: size, test FNR ----
__global__ __launch_bounds__(1024, 4) void k_final(const float* __restrict__ tres,
                                                   const int* __restrict__ tgt,
                                                   const float* __restrict__ lam,
                                                   const float* __restrict__ thr,
                                                   float* __restrict__ out) {
  __shared__ int r0[16];
  __shared__ int r1[16];
  __shared__ int r2[16];
  const int b = blockIdx.x, tid = threadIdx.x;
  const int lane = tid & 63, wv = tid >> 6;
  const float th = thr[b];
  const float* rb = tres + (size_t)b * NPIX;
  const int* gb = tgt + (size_t)b * NPIX;
  int sz = 0, tp = 0, tpos = 0;
  for (int p = tid; p < NPIX; p += 1024) {
    int pred = (rb[p] >= th) ? 1 : 0;
    int tg = (gb[p] > 0) ? 1 : 0;
    sz += pred;
    tp += pred & tg;
    tpos += tg;
  }
  #pragma unroll
  for (int off = 32; off; off >>= 1) {
    sz += __shfl_xor(sz, off);
    tp += __shfl_xor(tp, off);
    tpos += __shfl_xor(tpos, off);
  }
  if (lane == 0) { r0[wv] = sz; r1[wv] = tp; r2[wv] = tpos; }
  __syncthreads();
  if (tid == 0) {
    int s0 = 0, s1 = 0, s2 = 0;
    for (int w = 0; w < 16; ++w) { s0 += r0[w]; s1 += r1[w]; s2 += r2[w]; }
    float tposf = (float)(s2 > 0 ? s2 : 1);
    out[b] = 1.f - (float)s1 / tposf;   // fnr_test
    out[32 + b] = lam[b];               // lambda
    out[64 + b] = (float)s0;            // size
  }
}

extern "C" void kernel_launch(void* const* d_in, const int* in_sizes, int n_in,
                              void* d_out, int out_size, void* d_ws, size_t ws_size,
                              hipStream_t stream) {
  const float* cal_feat = (const float*)d_in[0];
  const float* test_feat = (const float*)d_in[1];
  const int* cal_gt = (const int*)d_in[2];
  const int* test_gt = (const int*)d_in[3];
  float* out = (float*)d_out;
  char* ws = (char*)d_ws;

  float* cal_res = (float*)(ws + OFF_CALRES);
  float* test_res = (float*)(ws + OFF_TESTRES);
  unsigned short* grouped = (unsigned short*)(ws + OFF_GROUPED);
  unsigned* cdf = (unsigned*)(ws + OFF_CDF);
  float* G = (float*)(ws + OFF_G);
  float* cc = (float*)(ws + OFF_CC);
  float* tt = (float*)(ws + OFF_TT);
  float* thr = (float*)(ws + OFF_THR);
  float* lam = (float*)(ws + OFF_LAM);

  k_cal<<<dim3(256), dim3(1024), 0, stream>>>(cal_feat, cal_gt, cal_res, cdf, grouped, cc);
  k_test<<<dim3(32), dim3(1024), 0, stream>>>(test_feat, test_res, tt, G);
  k_gemm<<<dim3(32, 32), dim3(256), 0, stream>>>(test_res, cal_res, G);
  k_quant<<<dim3(32), dim3(512), 0, stream>>>(G, cc, tt, cdf, grouped, lam, thr);
  k_final<<<dim3(32), dim3(1024), 0, stream>>>(test_res, test_gt, lam, thr, out);
}

// Round 4
// 287.745 us; speedup vs baseline: 3.3329x; 1.9455x over previous
//
#include <hip/hip_runtime.h>

// RandomlyLocalizedConformalRiskControl on MI355X.
// ws layout (bytes), total ~98.5 MB:
//   test_res f32 [32][65536]             @ 0          (8 MB)    f32 scores for k_final
//   cal_bf   u16 [256][65536]            @ 8388608    (32 MB)   bf16 cal scores (MFMA A/B)
//   test_bf  u16 [32][65536]             @ 41943040   (4 MB)    bf16 test scores
//   grouped  u16 [256][65536]            @ 46137344   (32 MB)   low-16 bits of f32 score, grouped by hi-16 bucket
//   cdf      u32 [256][CDF_STRIDE]       @ 79691776   (16 MB)   exclusive CDF over 16256 hi-16 buckets; [HB]=pos
//   gpart    f32 [64][8][1024]           @ 96354304   (2 MB)    split-K MFMA partials (deterministic, no atomics)
//   cc f32[256], tt f32[32], thr f32[32], lam f32[32]

#define NPIX 65536
#define HB 16256            // buckets = float_bits >> 16 for scores in (0, 1.0]
#define CDF_STRIDE 16272
#define ALPHA 0.1f

#define OFF_TESTRES  0
#define OFF_CALBF    8388608u
#define OFF_TESTBF   41943040u
#define OFF_GROUPED  46137344u
#define OFF_CDF      79691776u
#define OFF_GPART    96354304u
#define OFF_CC       98451456u
#define OFF_TT       98452480u
#define OFF_THR      98452608u
#define OFF_LAM      98452736u

typedef __attribute__((ext_vector_type(8))) short bf16x8;
typedef __attribute__((ext_vector_type(16))) float f32x16;

__device__ __forceinline__ unsigned short f2bf_rne(float f) {
  unsigned u = __float_as_uint(f);
  return (unsigned short)((u + 0x7FFFu + ((u >> 16) & 1u)) >> 16);
}

// ---- cal samples: features + histogram + CDF + register-held scatter + sum(sq on bf16) ----
// Scores held in 64 VGPRs/thread (full unroll) -> no f32 global round-trip, bit-exact phase B.
__global__ __launch_bounds__(1024, 4) void k_cal(const float* __restrict__ feat,
                                                 const int* __restrict__ gt,
                                                 unsigned short* __restrict__ calbf,
                                                 unsigned* __restrict__ cdf,
                                                 unsigned short* __restrict__ grouped,
                                                 float* __restrict__ cc) {
  __shared__ unsigned smem[16384];  // [0,HB): hist->counters; [16320..3] scan totals; [16336..51] cc partials
  __shared__ float sfeat[4096];
  const int n = blockIdx.x, tid = threadIdx.x;
  const int lane = tid & 63, wv = tid >> 6;
  for (int i = tid; i < HB; i += 1024) smem[i] = 0;
  for (int i = tid; i < 4096; i += 1024) sfeat[i] = feat[n * 4096 + i];
  const int* gtn = gt + (size_t)n * NPIX;
  unsigned short* cbn = calbf + (size_t)n * NPIX;
  const int x = tid & 255;
  const int yq = tid >> 8;  // 0..3
  float sx = 0.25f * (float)x - 0.375f;
  int x0 = (int)floorf(sx);
  float wx = sx - (float)x0;
  int x1 = x0 + 1;
  if (x0 < 0) x0 = 0;
  if (x1 > 63) x1 = 63;
  __syncthreads();
  float sv[64];
  unsigned long long pm = 0ull;
  float sumsq = 0.f;
  #pragma unroll 64
  for (int it = 0; it < 64; ++it) {
    int y = it * 4 + yq;
    float sy = 0.25f * (float)y - 0.375f;
    int y0 = (int)floorf(sy);
    float wy = sy - (float)y0;
    int y1 = y0 + 1;
    if (y0 < 0) y0 = 0;
    if (y1 > 63) y1 = 63;
    float a = sfeat[y0 * 64 + x0] * (1.f - wx) + sfeat[y0 * 64 + x1] * wx;
    float b = sfeat[y1 * 64 + x0] * (1.f - wx) + sfeat[y1 * 64 + x1] * wx;
    float v = a * (1.f - wy) + b * wy;
    float s = 1.f / (1.f + __expf(-v));
    int p = (y << 8) + x;
    unsigned short bh = f2bf_rne(s);
    cbn[p] = bh;
    float sr = __uint_as_float((unsigned)bh << 16);
    sumsq += sr * sr;
    sv[it] = s;
    if (gtn[p] > 0) {
      pm |= (1ull << it);
      atomicAdd(&smem[__float_as_uint(s) >> 16], 1u);
    }
  }
  // cc partials (16 waves)
  float ss = sumsq;
  #pragma unroll
  for (int off = 32; off; off >>= 1) ss += __shfl_xor(ss, off);
  if (lane == 0) smem[16336 + wv] = __float_as_uint(ss);
  __syncthreads();  // S1: hist + cc partials final
  if (tid == 0) {
    float c = 0.f;
    for (int w = 0; w < 16; ++w) c += __uint_as_float(smem[16336 + w]);
    cc[n] = c;
  }
  // exclusive scan of 16256 buckets on threads 0..255 (64/thread), wave shfl scan of partials
  unsigned* cdfn = cdf + (size_t)n * CDF_STRIDE;
  if (tid < 256) {
    const int base = tid * 64;
    unsigned psum = 0;
    if (base < HB) {
      for (int j = 0; j < 64; ++j) psum += smem[base + ((j + tid) & 63)];  // rotated: conflict-free
    }
    unsigned inc = psum;
    #pragma unroll
    for (int off = 1; off < 64; off <<= 1) {
      unsigned v = __shfl_up(inc, off);
      if (lane >= off) inc += v;
    }
    if (lane == 63) smem[16320 + wv] = inc;
  }
  __syncthreads();  // S2
  if (tid < 256) {
    const int base = tid * 64;
    unsigned psum = 0;
    if (base < HB) {
      for (int j = 0; j < 64; ++j) psum += smem[base + ((j + tid) & 63)];
    }
    unsigned inc = psum;
    #pragma unroll
    for (int off = 1; off < 64; off <<= 1) {
      unsigned v = __shfl_up(inc, off);
      if (lane >= off) inc += v;
    }
    unsigned woff = 0;
    for (int w = 0; w < wv; ++w) woff += smem[16320 + w];
    unsigned run = woff + inc - psum;
    if (base < HB) {
      for (int j = 0; j < 64; ++j) {
        unsigned hcnt = smem[base + j];
        cdfn[base + j] = run;
        smem[base + j] = run;  // becomes scatter counter
        run += hcnt;
      }
    }
    if (tid == 255) cdfn[HB] = woff + inc;  // total positives
  }
  __syncthreads();  // S3: counters ready
  // phase B: counting scatter of low-16 bits from registers (bit-exact with phase A)
  unsigned short* gn = grouped + (size_t)n * NPIX;
  #pragma unroll 64
  for (int it = 0; it < 64; ++it) {
    if (pm & (1ull << it)) {
      unsigned bits = __float_as_uint(sv[it]);
      unsigned idx = atomicAdd(&smem[bits >> 16], 1u);
      gn[idx] = (unsigned short)(bits & 0xFFFFu);
    }
  }
}

// ---- test samples: features (f32 + bf16) + sum(sq on bf16) ----
__global__ __launch_bounds__(1024, 4) void k_test(const float* __restrict__ feat,
                                                  float* __restrict__ res,
                                                  unsigned short* __restrict__ tbf,
                                                  float* __restrict__ tt) {
  __shared__ float sfeat[4096];
  __shared__ float red[16];
  const int b = blockIdx.x, tid = threadIdx.x;
  const int lane = tid & 63, wv = tid >> 6;
  for (int i = tid; i < 4096; i += 1024) sfeat[i] = feat[b * 4096 + i];
  float* resb = res + (size_t)b * NPIX;
  unsigned short* tbn = tbf + (size_t)b * NPIX;
  const int x = tid & 255;
  const int yq = tid >> 8;
  float sx = 0.25f * (float)x - 0.375f;
  int x0 = (int)floorf(sx);
  float wx = sx - (float)x0;
  int x1 = x0 + 1;
  if (x0 < 0) x0 = 0;
  if (x1 > 63) x1 = 63;
  __syncthreads();
  float sumsq = 0.f;
  for (int it = 0; it < 64; ++it) {
    int y = it * 4 + yq;
    float sy = 0.25f * (float)y - 0.375f;
    int y0 = (int)floorf(sy);
    float wy = sy - (float)y0;
    int y1 = y0 + 1;
    if (y0 < 0) y0 = 0;
    if (y1 > 63) y1 = 63;
    float a = sfeat[y0 * 64 + x0] * (1.f - wx) + sfeat[y0 * 64 + x1] * wx;
    float bb = sfeat[y1 * 64 + x0] * (1.f - wx) + sfeat[y1 * 64 + x1] * wx;
    float v = a * (1.f - wy) + bb * wy;
    float s = 1.f / (1.f + __expf(-v));
    int p = (y << 8) + x;
    resb[p] = s;
    unsigned short bh = f2bf_rne(s);
    tbn[p] = bh;
    float sr = __uint_as_float((unsigned)bh << 16);
    sumsq += sr * sr;
  }
  #pragma unroll
  for (int off = 32; off; off >>= 1) sumsq += __shfl_xor(sumsq, off);
  if (lane == 0) red[wv] = sumsq;
  __syncthreads();
  if (tid == 0) {
    float t = 0.f;
    for (int w = 0; w < 16; ++w) t += red[w];
    tt[b] = t;
  }
}

// ---- bf16 MFMA GEMM: gpart[ks][nt][m*32+nl] = <test_m, cal_(nt*32+nl)> over k-slice ks ----
// Wave computes a 32x32 tile via v_mfma_f32_32x32x16_bf16; accumulator in AGPRs (16/lane).
// A/B use identical lane->(row,k) mappings, so any intra-K permutation cancels in the dot product.
__global__ __launch_bounds__(256) void k_gemm(const unsigned short* __restrict__ tbf,
                                              const unsigned short* __restrict__ cbf,
                                              float* __restrict__ gpart) {
  __shared__ float lred[4][1024];
  const int tid = threadIdx.x;
  const int lane = tid & 63, wv = tid >> 6;
  const int r = lane & 31, half = lane >> 5;
  const int nt = blockIdx.x;              // 0..7: cal column tile
  const int ks = blockIdx.y;              // 0..63: K slice of 1024
  const size_t k0 = (size_t)ks * 1024 + wv * 256;
  const unsigned short* ta = tbf + (size_t)r * NPIX + k0 + (half << 3);
  const unsigned short* cb = cbf + (size_t)(nt * 32 + r) * NPIX + k0 + (half << 3);
  f32x16 acc;
  #pragma unroll
  for (int i = 0; i < 16; ++i) acc[i] = 0.f;
  #pragma unroll 4
  for (int kk = 0; kk < 256; kk += 16) {
    bf16x8 a = *(const bf16x8*)(ta + kk);
    bf16x8 b = *(const bf16x8*)(cb + kk);
    acc = __builtin_amdgcn_mfma_f32_32x32x16_bf16(a, b, acc, 0, 0, 0);
  }
  // C/D layout (HW-verified): col = lane&31, row = (reg&3) + 8*(reg>>2) + 4*(lane>>5)
  #pragma unroll
  for (int rg = 0; rg < 16; ++rg) {
    int m = (rg & 3) + 8 * (rg >> 2) + 4 * half;
    lred[wv][m * 32 + r] = acc[rg];
  }
  __syncthreads();
  float* gp = gpart + (size_t)(ks * 8 + nt) * 1024;
  for (int e = tid; e < 1024; e += 256)
    gp[e] = lred[0][e] + lred[1][e] + lred[2][e] + lred[3][e];
}

// ---- weights + direct weighted-quantile ----
// u* = inf{t : sum_n q_n*cnt_n(t) >= R}, R = ALPHA - wlast; 14-step binary search over the
// hi-16 bucket CDFs, then a 4096-bin weighted lo-16 histogram of the crossing bucket.
__global__ __launch_bounds__(512) void k_quant(const float* __restrict__ gpart,
                                               const float* __restrict__ cc,
                                               const float* __restrict__ tt,
                                               const unsigned* __restrict__ cdf,
                                               const unsigned short* __restrict__ grouped,
                                               float* __restrict__ lam,
                                               float* __restrict__ thr) {
  __shared__ float qs[256];
  __shared__ float bins[4096];
  __shared__ float red[8];
  __shared__ float bc[2];      // [0]=wsum, [1]=S(mid) broadcast
  __shared__ unsigned sBin;
  const int b = blockIdx.x, tid = threadIdx.x;
  const int lane = tid & 63, wv = tid >> 6;

  for (int i = tid; i < 4096; i += 512) bins[i] = 0.f;
  if (tid == 0) sBin = 0xFFFFFFFFu;

  // ---- weights: k_n = exp(-d2/8192), d2 = tt + cc - 2*sum_ks gpart ----
  float k = 0.f;
  if (tid < 256) {
    const float* gp = gpart + ((tid >> 5) * 1024) + (b * 32) + (tid & 31);
    float g = 0.f;
    #pragma unroll 8
    for (int ks = 0; ks < 64; ++ks) g += gp[(size_t)ks * 8192];
    float d2 = tt[b] + cc[tid] - 2.f * g;
    k = expf(-d2 * (1.f / 8192.f));
  }
  float v = k;
  #pragma unroll
  for (int off = 32; off; off >>= 1) v += __shfl_xor(v, off);
  if (lane == 0) red[wv] = v;
  __syncthreads();
  if (tid == 0) {
    float ws = 1.f;
    for (int w = 0; w < 8; ++w) ws += red[w];
    bc[0] = ws;
  }
  __syncthreads();
  const float wsum = bc[0];
  const float wlast = 1.f / wsum;
  const float R = ALPHA - wlast;
  if (R <= 0.f) {  // risk >= alpha for every lam -> low -> 1.0f, thr 0 (predict all)
    if (tid == 0) { lam[b] = 1.0f; thr[b] = 0.0f; }
    return;
  }
  if (tid < 256) {
    unsigned pos = cdf[(size_t)tid * CDF_STRIDE + HB];
    qs[tid] = k / (wsum * (float)(pos ? pos : 1u));
  }
  __syncthreads();

  // ---- 14-step binary search over hi-16 buckets: invariant S(lo) < R <= S(hi) ----
  int lo = 0, hi = HB;
  float baseS = 0.f;
  for (int it = 0; it < 14; ++it) {
    int mid = (lo + hi) >> 1;
    float p = 0.f;
    if (tid < 256) p = qs[tid] * (float)cdf[(size_t)tid * CDF_STRIDE + mid];
    float r = p;
    #pragma unroll
    for (int off = 32; off; off >>= 1) r += __shfl_xor(r, off);
    if (lane == 0) red[wv] = r;
    __syncthreads();
    if (tid == 0) {
      float s = 0.f;
      for (int w = 0; w < 8; ++w) s += red[w];
      bc[1] = s;
    }
    __syncthreads();
    float S = bc[1];
    if (S < R) { lo = mid; baseS = S; } else { hi = mid; }
  }
  const int B = lo;  // crossing bucket; baseS = weighted count below it

  // ---- gather bucket B members into 4096-bin weighted histogram of lo16>>4 ----
  {
    const int n = tid >> 1;
    const float q = qs[n];
    const unsigned* cn = cdf + (size_t)n * CDF_STRIDE;
    const unsigned short* gn = grouped + (size_t)n * NPIX;
    unsigned e0 = cn[B + 1];
    for (unsigned j = cn[B] + (tid & 1); j < e0; j += 2)
      atomicAdd(&bins[gn[j] >> 4], q);
  }
  __syncthreads();

  // ---- wave 0: scan 4096 bins, find crossing bin ----
  if (wv == 0) {
    float s = 0.f;
    for (int j = 0; j < 64; ++j) s += bins[lane * 64 + j];
    float inc = s;
    #pragma unroll
    for (int off = 1; off < 64; off <<= 1) {
      float u = __shfl_up(inc, off);
      if (lane >= off) inc += u;
    }
    float pre = inc - s;
    bool hit = (baseS + pre < R) && (baseS + inc >= R);
    unsigned long long m = __ballot(hit);
    int ow = m ? (__ffsll((unsigned long long)m) - 1) : -1;
    if (lane == ow) {
      float run = baseS + pre;
      unsigned bin = (unsigned)lane * 64 + 63;
      for (int j = 0; j < 64; ++j) {
        float bv = bins[lane * 64 + j];
        if (run + bv >= R) { bin = (unsigned)lane * 64 + j; break; }
        run += bv;
      }
      sBin = bin;
    }
    if (m == 0 && lane == 0) sBin = 4095u;  // f32-rounding fallback (unreachable in practice)
  }
  __syncthreads();
  if (tid == 0) {
    unsigned tb = ((unsigned)B << 16) | (sBin << 4);
    lam[b] = 1.0f - __uint_as_float(tb | 0x8u);     // mid-bin representative
    thr[b] = __uint_as_float((tb | 0xFu) + 1u);     // strictly above bin top: pred = res > u*
  }
}

// ---- final: size, test FNR ----
__global__ __launch_bounds__(1024, 4) void k_final(const float* __restrict__ tres,
                                                   const int* __restrict__ tgt,
                                                   const float* __restrict__ lam,
                                                   const float* __restrict__ thr,
                                                   float* __restrict__ out) {
  __shared__ int r0[16];
  __shared__ int r1[16];
  __shared__ int r2[16];
  const int b = blockIdx.x, tid = threadIdx.x;
  const int lane = tid & 63, wv = tid >> 6;
  const float th = thr[b];
  const float* rb = tres + (size_t)b * NPIX;
  const int* gb = tgt + (size_t)b * NPIX;
  int sz = 0, tp = 0, tpos = 0;
  for (int p = tid; p < NPIX; p += 1024) {
    int pred = (rb[p] >= th) ? 1 : 0;
    int tg = (gb[p] > 0) ? 1 : 0;
    sz += pred;
    tp += pred & tg;
    tpos += tg;
  }
  #pragma unroll
  for (int off = 32; off; off >>= 1) {
    sz += __shfl_xor(sz, off);
    tp += __shfl_xor(tp, off);
    tpos += __shfl_xor(tpos, off);
  }
  if (lane == 0) { r0[wv] = sz; r1[wv] = tp; r2[wv] = tpos; }
  __syncthreads();
  if (tid == 0) {
    int s0 = 0, s1 = 0, s2 = 0;
    for (int w = 0; w < 16; ++w) { s0 += r0[w]; s1 += r1[w]; s2 += r2[w]; }
    float tposf = (float)(s2 > 0 ? s2 : 1);
    out[b] = 1.f - (float)s1 / tposf;   // fnr_test
    out[32 + b] = lam[b];               // lambda
    out[64 + b] = (float)s0;            // size
  }
}

extern "C" void kernel_launch(void* const* d_in, const int* in_sizes, int n_in,
                              void* d_out, int out_size, void* d_ws, size_t ws_size,
                              hipStream_t stream) {
  const float* cal_feat = (const float*)d_in[0];
  const float* test_feat = (const float*)d_in[1];
  const int* cal_gt = (const int*)d_in[2];
  const int* test_gt = (const int*)d_in[3];
  float* out = (float*)d_out;
  char* ws = (char*)d_ws;

  float* test_res = (float*)(ws + OFF_TESTRES);
  unsigned short* cal_bf = (unsigned short*)(ws + OFF_CALBF);
  unsigned short* test_bf = (unsigned short*)(ws + OFF_TESTBF);
  unsigned short* grouped = (unsigned short*)(ws + OFF_GROUPED);
  unsigned* cdf = (unsigned*)(ws + OFF_CDF);
  float* gpart = (float*)(ws + OFF_GPART);
  float* cc = (float*)(ws + OFF_CC);
  float* tt = (float*)(ws + OFF_TT);
  float* thr = (float*)(ws + OFF_THR);
  float* lam = (float*)(ws + OFF_LAM);

  k_cal<<<dim3(256), dim3(1024), 0, stream>>>(cal_feat, cal_gt, cal_bf, cdf, grouped, cc);
  k_test<<<dim3(32), dim3(1024), 0, stream>>>(test_feat, test_res, test_bf, tt);
  k_gemm<<<dim3(8, 64), dim3(256), 0, stream>>>(test_bf, cal_bf, gpart);
  k_quant<<<dim3(32), dim3(512), 0, stream>>>(gpart, cc, tt, cdf, grouped, lam, thr);
  k_final<<<dim3(32), dim3(1024), 0, stream>>>(test_res, test_gt, lam, thr, out);
}

// Round 5
// 245.720 us; speedup vs baseline: 3.9029x; 1.1710x over previous
//
#include <hip/hip_runtime.h>

// RandomlyLocalizedConformalRiskControl on MI355X.
// ws layout (bytes), total ~98.5 MB:
//   test_res f32 [32][65536]             @ 0          (8 MB)    f32 scores for k_finalp
//   cal_bf   u16 [256][65536]            @ 8388608    (32 MB)   bf16 cal scores (MFMA A/B)
//   test_bf  u16 [32][65536]             @ 41943040   (4 MB)    bf16 test scores
//   grouped  u16 [256][65536]            @ 46137344   (32 MB)   low-16 bits of f32 score, grouped by hi-16 bucket
//   cdf      u32 [256][CDF_STRIDE]       @ 79691776   (16 MB)   exclusive CDF over 16256 hi-16 buckets; [HB]=pos
//   gpart    f32 [64][8][1024]           @ 96354304   (2 MB)    split-K MFMA partials (deterministic)
//   cc f32[256], tt f32[32], thr f32[32], lam f32[32], facc i32[32][4]

#define NPIX 65536
#define HB 16256            // buckets = float_bits >> 16 for scores in (0, 1.0]
#define CDF_STRIDE 16272
#define ALPHA 0.1f

#define OFF_TESTRES  0
#define OFF_CALBF    8388608u
#define OFF_TESTBF   41943040u
#define OFF_GROUPED  46137344u
#define OFF_CDF      79691776u
#define OFF_GPART    96354304u
#define OFF_CC       98451456u
#define OFF_TT       98452480u
#define OFF_THR      98452608u
#define OFF_LAM      98452736u
#define OFF_FACC     98452864u

typedef __attribute__((ext_vector_type(8))) short bf16x8;
typedef __attribute__((ext_vector_type(16))) float f32x16;

__device__ __forceinline__ unsigned short f2bf_rne(float f) {
  unsigned u = __float_as_uint(f);
  return (unsigned short)((u + 0x7FFFu + ((u >> 16) & 1u)) >> 16);
}

// Shared by phase A and phase B (and cal/test paths): identical inlined expression tree
// -> identical FMA contraction -> bit-identical f32 result on recompute.
__device__ __forceinline__ float score_at(const float* __restrict__ sfeat,
                                          int x0, int x1, float wx, int y) {
  float sy = 0.25f * (float)y - 0.375f;
  int y0 = (int)floorf(sy);
  float wy = sy - (float)y0;
  int y1 = y0 + 1;
  if (y0 < 0) y0 = 0;
  if (y1 > 63) y1 = 63;
  float a = sfeat[y0 * 64 + x0] * (1.f - wx) + sfeat[y0 * 64 + x1] * wx;
  float b = sfeat[y1 * 64 + x0] * (1.f - wx) + sfeat[y1 * 64 + x1] * wx;
  float v = a * (1.f - wy) + b * wy;
  return 1.f / (1.f + __expf(-v));
}

// ---- fused cal+test features ----
// blocks 0..255: cal sample n = blockIdx.x (hist + CDF + scatter + bf16 + cc)
// blocks 256..287: test sample b = blockIdx.x-256 (f32 + bf16 + tt)
// LDS exactly 81920 B -> 2 blocks/CU co-residency; VGPR capped 64 (no spill: sv[] removed,
// phase B recomputes scores from LDS-resident features, masked by pm).
__global__ __launch_bounds__(1024, 8) void k_calt(const float* __restrict__ featc,
                                                  const int* __restrict__ gt,
                                                  unsigned short* __restrict__ calbf,
                                                  unsigned* __restrict__ cdf,
                                                  unsigned short* __restrict__ grouped,
                                                  float* __restrict__ cc,
                                                  const float* __restrict__ featt,
                                                  float* __restrict__ tres,
                                                  unsigned short* __restrict__ tbf,
                                                  float* __restrict__ tt) {
  __shared__ unsigned smem[16384];  // cal: [0,HB) hist->counters; [16320..]: scan totals; [16336..]: cc partials. test: [0..15] reduce
  __shared__ float sfeat[4096];
  const int tid = threadIdx.x;
  const int lane = tid & 63, wv = tid >> 6;
  const int x = tid & 255, yq = tid >> 8;  // yq in 0..3
  float sx = 0.25f * (float)x - 0.375f;
  int x0 = (int)floorf(sx);
  float wx = sx - (float)x0;
  int x1 = x0 + 1;
  if (x0 < 0) x0 = 0;
  if (x1 > 63) x1 = 63;

  if (blockIdx.x >= 256) {
    // ---- test path ----
    const int b = blockIdx.x - 256;
    for (int i = tid; i < 4096; i += 1024) sfeat[i] = featt[b * 4096 + i];
    __syncthreads();
    float* resb = tres + (size_t)b * NPIX;
    unsigned short* tbn = tbf + (size_t)b * NPIX;
    float sumsq = 0.f;
    #pragma unroll 4
    for (int it = 0; it < 64; ++it) {
      int y = it * 4 + yq;
      float s = score_at(sfeat, x0, x1, wx, y);
      int p = (y << 8) + x;
      resb[p] = s;
      unsigned short bh = f2bf_rne(s);
      tbn[p] = bh;
      float sr = __uint_as_float((unsigned)bh << 16);
      sumsq += sr * sr;
    }
    #pragma unroll
    for (int off = 32; off; off >>= 1) sumsq += __shfl_xor(sumsq, off);
    if (lane == 0) smem[wv] = __float_as_uint(sumsq);
    __syncthreads();
    if (tid == 0) {
      float t = 0.f;
      for (int w = 0; w < 16; ++w) t += __uint_as_float(smem[w]);
      tt[b] = t;
    }
    return;
  }

  // ---- cal path ----
  const int n = blockIdx.x;
  for (int i = tid; i < HB; i += 1024) smem[i] = 0;
  for (int i = tid; i < 4096; i += 1024) sfeat[i] = featc[n * 4096 + i];
  const int* gtn = gt + (size_t)n * NPIX;
  unsigned short* cbn = calbf + (size_t)n * NPIX;
  __syncthreads();
  unsigned long long pm = 0ull;
  float sumsq = 0.f;
  #pragma unroll 4
  for (int it = 0; it < 64; ++it) {
    int y = it * 4 + yq;
    float s = score_at(sfeat, x0, x1, wx, y);
    int p = (y << 8) + x;
    unsigned short bh = f2bf_rne(s);
    cbn[p] = bh;
    float sr = __uint_as_float((unsigned)bh << 16);
    sumsq += sr * sr;
    if (gtn[p] > 0) {
      pm |= (1ull << it);
      atomicAdd(&smem[__float_as_uint(s) >> 16], 1u);
    }
  }
  // cc partials (16 waves)
  #pragma unroll
  for (int off = 32; off; off >>= 1) sumsq += __shfl_xor(sumsq, off);
  if (lane == 0) smem[16336 + wv] = __float_as_uint(sumsq);
  __syncthreads();  // S1: hist + cc partials final
  if (tid == 0) {
    float c = 0.f;
    for (int w = 0; w < 16; ++w) c += __uint_as_float(smem[16336 + w]);
    cc[n] = c;
  }
  // exclusive scan of 16256 buckets on threads 0..255 (64/thread), wave shfl scan of partials
  unsigned* cdfn = cdf + (size_t)n * CDF_STRIDE;
  if (tid < 256) {
    const int base = tid * 64;
    unsigned psum = 0;
    if (base < HB) {
      for (int j = 0; j < 64; ++j) psum += smem[base + ((j + tid) & 63)];  // rotated: conflict-free
    }
    unsigned inc = psum;
    #pragma unroll
    for (int off = 1; off < 64; off <<= 1) {
      unsigned v = __shfl_up(inc, off);
      if (lane >= off) inc += v;
    }
    if (lane == 63) smem[16320 + wv] = inc;
  }
  __syncthreads();  // S2
  if (tid < 256) {
    const int base = tid * 64;
    unsigned psum = 0;
    if (base < HB) {
      for (int j = 0; j < 64; ++j) psum += smem[base + ((j + tid) & 63)];
    }
    unsigned inc = psum;
    #pragma unroll
    for (int off = 1; off < 64; off <<= 1) {
      unsigned v = __shfl_up(inc, off);
      if (lane >= off) inc += v;
    }
    unsigned woff = 0;
    for (int w = 0; w < wv; ++w) woff += smem[16320 + w];
    unsigned run = woff + inc - psum;
    if (base < HB) {
      for (int j = 0; j < 64; ++j) {
        unsigned hcnt = smem[base + j];
        cdfn[base + j] = run;
        smem[base + j] = run;  // becomes scatter counter
        run += hcnt;
      }
    }
    if (tid == 255) cdfn[HB] = woff + inc;  // total positives
  }
  __syncthreads();  // S3: counters ready
  // phase B: recompute scores (bit-exact via shared score_at) for positives, counting scatter
  unsigned short* gn = grouped + (size_t)n * NPIX;
  for (int it = 0; it < 64; ++it) {
    if (pm & (1ull << it)) {
      int y = it * 4 + yq;
      float s = score_at(sfeat, x0, x1, wx, y);
      unsigned bits = __float_as_uint(s);
      unsigned idx = atomicAdd(&smem[bits >> 16], 1u);
      gn[idx] = (unsigned short)(bits & 0xFFFFu);
    }
  }
}

// ---- LDS-staged bf16 MFMA GEMM: gpart[ks][nt][m*32+nl] = <test_m, cal_(nt*32+nl)> ----
// Coalesced 1KB/wave global loads into XOR-swizzled [kblk][row][16B] tiles; ds_read_b128
// fragments; wave = K-quarter split, cross-wave reduce in lred. 80 KB LDS -> 2 blocks/CU.
__global__ __launch_bounds__(256) void k_gemm(const unsigned short* __restrict__ tbf,
                                              const unsigned short* __restrict__ cbf,
                                              float* __restrict__ gpart) {
  __shared__ __align__(16) unsigned short As[16384];  // 32 KB: 64 kblk x 32 row x 8 elems
  __shared__ __align__(16) unsigned short Bs[16384];
  __shared__ float lred[4][1024];                     // 16 KB
  const int tid = threadIdx.x;
  const int lane = tid & 63, wv = tid >> 6;
  const int r = lane & 31, half = lane >> 5;
  const int nt = blockIdx.x;              // 0..7: cal column tile
  f32x16 acc;
  #pragma unroll
  for (int i = 0; i < 16; ++i) acc[i] = 0.f;
  for (int ch = 0; ch < 2; ++ch) {        // two 512-K chunks of this block's 1024-K slice
    const size_t kbase = (size_t)blockIdx.y * 1024 + ch * 512;
    __syncthreads();
    #pragma unroll
    for (int s = 0; s < 16; ++s) {
      int flat = s * 256 + tid;           // 0..4095; <2048 = A, else B (wave-uniform per s)
      int rem = flat & 2047;
      int row = rem >> 6, kb = rem & 63;
      const unsigned short* src = (flat >= 2048)
          ? cbf + (size_t)(nt * 32 + row) * NPIX + kbase + kb * 8
          : tbf + (size_t)row * NPIX + kbase + kb * 8;
      int slot = ((kb << 5) + row) ^ (kb & 31);   // XOR swizzle breaks write-bank collisions
      int4 v = *(const int4*)src;
      *(int4*)((flat >= 2048 ? Bs : As) + slot * 8) = v;
    }
    __syncthreads();
    #pragma unroll
    for (int i = 0; i < 8; ++i) {         // wave's K-quarter: kblk in [wv*16, wv*16+16)
      int k8 = (wv << 4) + i * 2 + half;
      int slot = ((k8 << 5) + r) ^ (k8 & 31);
      bf16x8 a = *(const bf16x8*)(As + slot * 8);
      bf16x8 b = *(const bf16x8*)(Bs + slot * 8);
      acc = __builtin_amdgcn_mfma_f32_32x32x16_bf16(a, b, acc, 0, 0, 0);
    }
  }
  // C/D layout (HW-verified): col = lane&31, row = (reg&3) + 8*(reg>>2) + 4*(lane>>5)
  #pragma unroll
  for (int rg = 0; rg < 16; ++rg) {
    int m = (rg & 3) + 8 * (rg >> 2) + 4 * half;
    lred[wv][m * 32 + r] = acc[rg];
  }
  __syncthreads();
  float* gp = gpart + (size_t)(blockIdx.y * 8 + nt) * 1024;
  for (int e = tid; e < 1024; e += 256)
    gp[e] = lred[0][e] + lred[1][e] + lred[2][e] + lred[3][e];
}

// ---- weights + direct weighted-quantile; also zero-inits facc for k_finalp ----
__global__ __launch_bounds__(512) void k_quant(const float* __restrict__ gpart,
                                               const float* __restrict__ cc,
                                               const float* __restrict__ tt,
                                               const unsigned* __restrict__ cdf,
                                               const unsigned short* __restrict__ grouped,
                                               float* __restrict__ lam,
                                               float* __restrict__ thr,
                                               int* __restrict__ facc) {
  __shared__ float qs[256];
  __shared__ float bins[4096];
  __shared__ float red[8];
  __shared__ float bc[2];      // [0]=wsum, [1]=S(mid) broadcast
  __shared__ unsigned sBin;
  const int b = blockIdx.x, tid = threadIdx.x;
  const int lane = tid & 63, wv = tid >> 6;

  if (tid < 4) facc[b * 4 + tid] = 0;
  for (int i = tid; i < 4096; i += 512) bins[i] = 0.f;
  if (tid == 0) sBin = 0xFFFFFFFFu;

  // ---- weights: k_n = exp(-d2/8192), d2 = tt + cc - 2*sum_ks gpart ----
  float k = 0.f;
  if (tid < 256) {
    const float* gp = gpart + ((tid >> 5) * 1024) + (b * 32) + (tid & 31);
    float g = 0.f;
    #pragma unroll 8
    for (int ks = 0; ks < 64; ++ks) g += gp[(size_t)ks * 8192];
    float d2 = tt[b] + cc[tid] - 2.f * g;
    k = expf(-d2 * (1.f / 8192.f));
  }
  float v = k;
  #pragma unroll
  for (int off = 32; off; off >>= 1) v += __shfl_xor(v, off);
  if (lane == 0) red[wv] = v;
  __syncthreads();
  if (tid == 0) {
    float ws = 1.f;
    for (int w = 0; w < 8; ++w) ws += red[w];
    bc[0] = ws;
  }
  __syncthreads();
  const float wsum = bc[0];
  const float wlast = 1.f / wsum;
  const float R = ALPHA - wlast;
  if (R <= 0.f) {  // risk >= alpha for every lam -> low -> 1.0f, thr 0 (predict all)
    if (tid == 0) { lam[b] = 1.0f; thr[b] = 0.0f; }
    return;
  }
  if (tid < 256) {
    unsigned pos = cdf[(size_t)tid * CDF_STRIDE + HB];
    qs[tid] = k / (wsum * (float)(pos ? pos : 1u));
  }
  __syncthreads();

  // ---- 14-step binary search over hi-16 buckets: invariant S(lo) < R <= S(hi) ----
  int lo = 0, hi = HB;
  float baseS = 0.f;
  for (int it = 0; it < 14; ++it) {
    int mid = (lo + hi) >> 1;
    float p = 0.f;
    if (tid < 256) p = qs[tid] * (float)cdf[(size_t)tid * CDF_STRIDE + mid];
    float r = p;
    #pragma unroll
    for (int off = 32; off; off >>= 1) r += __shfl_xor(r, off);
    if (lane == 0) red[wv] = r;
    __syncthreads();
    if (tid == 0) {
      float s = 0.f;
      for (int w = 0; w < 8; ++w) s += red[w];
      bc[1] = s;
    }
    __syncthreads();
    float S = bc[1];
    if (S < R) { lo = mid; baseS = S; } else { hi = mid; }
  }
  const int B = lo;  // crossing bucket; baseS = weighted count below it

  // ---- gather bucket B members into 4096-bin weighted histogram of lo16>>4 ----
  {
    const int n = tid >> 1;
    const float q = qs[n];
    const unsigned* cn = cdf + (size_t)n * CDF_STRIDE;
    const unsigned short* gn = grouped + (size_t)n * NPIX;
    unsigned e0 = cn[B + 1];
    for (unsigned j = cn[B] + (tid & 1); j < e0; j += 2)
      atomicAdd(&bins[gn[j] >> 4], q);
  }
  __syncthreads();

  // ---- wave 0: scan 4096 bins, find crossing bin ----
  if (wv == 0) {
    float s = 0.f;
    for (int j = 0; j < 64; ++j) s += bins[lane * 64 + j];
    float inc = s;
    #pragma unroll
    for (int off = 1; off < 64; off <<= 1) {
      float u = __shfl_up(inc, off);
      if (lane >= off) inc += u;
    }
    float pre = inc - s;
    bool hit = (baseS + pre < R) && (baseS + inc >= R);
    unsigned long long m = __ballot(hit);
    int ow = m ? (__ffsll((unsigned long long)m) - 1) : -1;
    if (lane == ow) {
      float run = baseS + pre;
      unsigned bin = (unsigned)lane * 64 + 63;
      for (int j = 0; j < 64; ++j) {
        float bv = bins[lane * 64 + j];
        if (run + bv >= R) { bin = (unsigned)lane * 64 + j; break; }
        run += bv;
      }
      sBin = bin;
    }
    if (m == 0 && lane == 0) sBin = 4095u;  // f32-rounding fallback (unreachable in practice)
  }
  __syncthreads();
  if (tid == 0) {
    unsigned tb = ((unsigned)B << 16) | (sBin << 4);
    lam[b] = 1.0f - __uint_as_float(tb | 0x8u);     // mid-bin representative
    thr[b] = __uint_as_float((tb | 0xFu) + 1u);     // strictly above bin top: pred = res > u*
  }
}

// ---- final partials: grid (32 samples, 8 segments), atomic int accumulate ----
__global__ __launch_bounds__(256) void k_finalp(const float* __restrict__ tres,
                                                const int* __restrict__ tgt,
                                                const float* __restrict__ thr,
                                                int* __restrict__ facc) {
  __shared__ int red[12];
  const int b = blockIdx.x, seg = blockIdx.y, tid = threadIdx.x;
  const int lane = tid & 63, wv = tid >> 6;
  const float th = thr[b];
  const float* rb = tres + (size_t)b * NPIX + seg * 8192;
  const int* gb = tgt + (size_t)b * NPIX + seg * 8192;
  int sz = 0, tp = 0, tpos = 0;
  for (int i = 0; i < 32; ++i) {
    int p = i * 256 + tid;
    int pred = (rb[p] >= th) ? 1 : 0;
    int tg = (gb[p] > 0) ? 1 : 0;
    sz += pred;
    tp += pred & tg;
    tpos += tg;
  }
  #pragma unroll
  for (int off = 32; off; off >>= 1) {
    sz += __shfl_xor(sz, off);
    tp += __shfl_xor(tp, off);
    tpos += __shfl_xor(tpos, off);
  }
  if (lane == 0) { red[wv] = sz; red[4 + wv] = tp; red[8 + wv] = tpos; }
  __syncthreads();
  if (tid == 0) {
    int s0 = red[0] + red[1] + red[2] + red[3];
    int s1 = red[4] + red[5] + red[6] + red[7];
    int s2 = red[8] + red[9] + red[10] + red[11];
    atomicAdd(&facc[b * 4 + 0], s0);
    atomicAdd(&facc[b * 4 + 1], s1);
    atomicAdd(&facc[b * 4 + 2], s2);
  }
}

// ---- emit outputs ----
__global__ void k_out(const int* __restrict__ facc, const float* __restrict__ lam,
                      float* __restrict__ out) {
  int b = threadIdx.x;
  if (b < 32) {
    int sz = facc[b * 4], tp = facc[b * 4 + 1], tpos = facc[b * 4 + 2];
    float tposf = (float)(tpos > 0 ? tpos : 1);
    out[b] = 1.f - (float)tp / tposf;   // fnr_test
    out[32 + b] = lam[b];               // lambda
    out[64 + b] = (float)sz;            // size
  }
}

extern "C" void kernel_launch(void* const* d_in, const int* in_sizes, int n_in,
                              void* d_out, int out_size, void* d_ws, size_t ws_size,
                              hipStream_t stream) {
  const float* cal_feat = (const float*)d_in[0];
  const float* test_feat = (const float*)d_in[1];
  const int* cal_gt = (const int*)d_in[2];
  const int* test_gt = (const int*)d_in[3];
  float* out = (float*)d_out;
  char* ws = (char*)d_ws;

  float* test_res = (float*)(ws + OFF_TESTRES);
  unsigned short* cal_bf = (unsigned short*)(ws + OFF_CALBF);
  unsigned short* test_bf = (unsigned short*)(ws + OFF_TESTBF);
  unsigned short* grouped = (unsigned short*)(ws + OFF_GROUPED);
  unsigned* cdf = (unsigned*)(ws + OFF_CDF);
  float* gpart = (float*)(ws + OFF_GPART);
  float* cc = (float*)(ws + OFF_CC);
  float* tt = (float*)(ws + OFF_TT);
  float* thr = (float*)(ws + OFF_THR);
  float* lam = (float*)(ws + OFF_LAM);
  int* facc = (int*)(ws + OFF_FACC);

  k_calt<<<dim3(288), dim3(1024), 0, stream>>>(cal_feat, cal_gt, cal_bf, cdf, grouped, cc,
                                               test_feat, test_res, test_bf, tt);
  k_gemm<<<dim3(8, 64), dim3(256), 0, stream>>>(test_bf, cal_bf, gpart);
  k_quant<<<dim3(32), dim3(512), 0, stream>>>(gpart, cc, tt, cdf, grouped, lam, thr, facc);
  k_finalp<<<dim3(32, 8), dim3(256), 0, stream>>>(test_res, test_gt, thr, facc);
  k_out<<<dim3(1), dim3(64), 0, stream>>>(facc, lam, out);
}